// Round 8
// baseline (246.130 us; speedup 1.0000x reference)
//
#include <hip/hip_runtime.h>
#include <hip/hip_bf16.h>

// B=2, T=2048, C=1024, H=16, HD=64. f32 I/O; bf16 MFMA internally, f32 accum.
//
//   0) prep (fused): x -> xb bf16; w_qkv,w_out -> bf16 W^T[N][K]
//   1) gemm_glds<EPI=1,BN=128>: qkv proj (BK=64, XOR-swizzled LDS, glds16).
//      Q pre-scaled 0.125*log2e -> qk; K -> qk; V -> vt[B,H,64,T].
//   2) attn_mfma: flash attention, static exp2 softmax. 256-thr / 4-wave
//      blocks, band map: block t owns Q rows [64t,64t+64), nch=t+1, LPT.
//      2x2 wave split (round-7, verified): wave w = q-half wq=w&1 x
//      key-half ws=w>>1; P feeds PV's A-frag directly from registers.
//      ROUND-8: the LDS pipe was the bound (~1630 cyc/CU/chunk-round ~=
//      measured attn time). K and V fragment reads are LINE-EXACT from
//      global (quads tile full 64B lines, like the Q af loads) -> read
//      K (4xb128) and V (8xb64) DIRECT from L1/L2 each chunk. No Kl/Vl,
//      no glds16, no double-buffer, NO in-loop barriers; waves fully
//      independent. L2 traffic ~270MB total (~15 B/cyc/CU - trivial).
//      Also: l via ones-MFMA - mfma(pf, ones, O1) per qt replaces 16 VALU
//      adds/chunk + all epilogue shuffles; lr[r] = O1[qt][r] directly.
//      LDS = 20KB merge buffer only (one barrier in kernel). All O/O1
//      indices compile-time (rule #20). VGPR ~130 under cap 170 ->
//      3 blocks/CU = 12 waves/CU.
//   3) gemm_glds<EPI=0,BN=64>: out proj -> d_out f32

#define B_ 2
#define T_ 2048
#define C_ 1024
#define H_ 16
#define HD_ 64
#define M_ (B_ * T_)      // 4096
#define N3_ (3 * C_)      // 3072
#define QK2_ 2048
#define QSCALE 0.18033688f   // 0.125 * log2(e)

typedef __attribute__((ext_vector_type(8))) short short8;
typedef __attribute__((ext_vector_type(4))) short short4v;
typedef __attribute__((ext_vector_type(4))) float floatx4;

__device__ __forceinline__ unsigned short f2b(float f) {
    __hip_bfloat16 h = __float2bfloat16(f);
    return *reinterpret_cast<unsigned short*>(&h);
}

__device__ __forceinline__ float fexp2(float x) {
#if __has_builtin(__builtin_amdgcn_exp2f)
    return __builtin_amdgcn_exp2f(x);
#else
    return exp2f(x);
#endif
}

__device__ __forceinline__ void glds16(const void* g, void* l) {
    __builtin_amdgcn_global_load_lds(
        (const __attribute__((address_space(1))) void*)g,
        (__attribute__((address_space(3))) void*)l, 16, 0, 0);
}

// ---------------------------------------------------------------------------
// Fused prep. seg0 (4096 blocks): x f32->bf16. seg1 (1536): w_qkv -> wt1
// [3072][1024] via 64(k)x32(n) tiles, short8 coalesced writes. seg2 (512):
// w_out -> wt2.
// ---------------------------------------------------------------------------
__global__ __launch_bounds__(256) void prep(
    const float* __restrict__ x, const float* __restrict__ w_qkv,
    const float* __restrict__ w_out, unsigned short* __restrict__ xb,
    unsigned short* __restrict__ wt1, unsigned short* __restrict__ wt2) {
    __shared__ float t[64][33];
    const int bi = blockIdx.x;
    const int tid = threadIdx.x;
    if (bi < 4096) {
        int i = (bi * 256 + tid) * 4;
        float4 v = *reinterpret_cast<const float4*>(x + i);
        short4v s;
        s[0] = (short)f2b(v.x); s[1] = (short)f2b(v.y);
        s[2] = (short)f2b(v.z); s[3] = (short)f2b(v.w);
        *reinterpret_cast<short4v*>(xb + i) = s;
        return;
    }
    const float* src; unsigned short* dst; int n0, k0, N;
    if (bi < 4096 + 1536) {
        int u = bi - 4096;
        src = w_qkv; dst = wt1; N = N3_;
        k0 = (u & 15) * 64; n0 = (u >> 4) * 32;
    } else {
        int u = bi - (4096 + 1536);
        src = w_out; dst = wt2; N = C_;
        k0 = (u & 15) * 64; n0 = (u >> 4) * 32;
    }
    const int tx = tid & 31, ty = tid >> 5;
#pragma unroll
    for (int i = 0; i < 8; i++)
        t[ty + i * 8][tx] = src[(size_t)(k0 + ty + i * 8) * N + n0 + tx];
    __syncthreads();
    const int row = tid >> 3;
    const int kp  = (tid & 7) * 8;
    short8 o;
#pragma unroll
    for (int j = 0; j < 8; j++) o[j] = (short)f2b(t[kp + j][row]);
    *reinterpret_cast<short8*>(&dst[(size_t)(n0 + row) * C_ + k0 + kp]) = o;
}

// ---------------------------------------------------------------------------
// GEMM: C[M,N] = A[M,K] @ Bt^T[N,K] + bias[N]. A,Bt bf16. Tile 128 x BN,
// BK=64, 4 waves 2x2. LDS rows 64 shorts, XOR chunk swizzle; glds16 staging.
// 1D grid, XCD-banded (neutral-at-worst heuristic).
// ---------------------------------------------------------------------------
template<int EPI, int BN>
__global__ __launch_bounds__(256) void gemm_glds(
    const unsigned short* __restrict__ A, const unsigned short* __restrict__ Bt,
    const float* __restrict__ bias, void* __restrict__ Cp,
    unsigned short* __restrict__ vtp, int M, int N, int K) {
    constexpr int NI = BN / 32;
    __shared__ __align__(16) unsigned short Al[128 * 64];
    __shared__ __align__(16) unsigned short Bl[BN * 64];

    const int tid  = threadIdx.x;
    const int lane = tid & 63;
    const int w    = tid >> 6;
    const int c16  = lane & 15;
    const int quad = lane >> 4;
    const int NT  = N / BN;
    const int pe  = NT >> 3;
    const int xcd = blockIdx.x & 7;
    const int ii  = blockIdx.x >> 3;
    const int n0  = (xcd * pe + ii % pe) * BN;
    const int m0  = (ii / pe) * 128;
    const int wm = (w >> 1) * 64;
    const int wn = (w & 1) * (BN / 2);

    floatx4 acc[4][NI] = {};

    const int srow = lane >> 3;
    const int sch  = ((lane & 7) ^ srow) * 8;
    const unsigned short* ag = A + (size_t)(m0 + w * 32 + srow) * K + sch;
    const unsigned short* bg = Bt + (size_t)(n0 + w * (BN / 4) + srow) * K + sch;

    const int s7 = c16 & 7;

    for (int k0 = 0; k0 < K; k0 += 64) {
        __syncthreads();
#pragma unroll
        for (int i = 0; i < 4; i++)
            glds16(ag + k0 + (size_t)(i * 8) * K, &Al[(w * 32 + i * 8) * 64]);
#pragma unroll
        for (int i = 0; i < BN / 32; i++)
            glds16(bg + k0 + (size_t)(i * 8) * K,
                   &Bl[(w * (BN / 4) + i * 8) * 64]);
        __syncthreads();

        short8 af[4][2], bf[NI][2];
#pragma unroll
        for (int im = 0; im < 4; im++)
#pragma unroll
            for (int kk = 0; kk < 2; kk++)
                af[im][kk] = *reinterpret_cast<const short8*>(
                    &Al[(wm + im * 16 + c16) * 64 + ((kk * 4 + quad) ^ s7) * 8]);
#pragma unroll
        for (int in = 0; in < NI; in++)
#pragma unroll
            for (int kk = 0; kk < 2; kk++)
                bf[in][kk] = *reinterpret_cast<const short8*>(
                    &Bl[(wn + in * 16 + c16) * 64 + ((kk * 4 + quad) ^ s7) * 8]);
#pragma unroll
        for (int im = 0; im < 4; im++)
#pragma unroll
            for (int in = 0; in < NI; in++)
#pragma unroll
                for (int kk = 0; kk < 2; kk++)
                    acc[im][in] = __builtin_amdgcn_mfma_f32_16x16x32_bf16(
                        af[im][kk], bf[in][kk], acc[im][in], 0, 0, 0);
    }

    const int ncol = n0 + wn;
    float bv[NI];
#pragma unroll
    for (int in = 0; in < NI; in++) bv[in] = bias[ncol + in * 16 + c16];

    if (EPI == 0) {
        float* C = (float*)Cp;
#pragma unroll
        for (int im = 0; im < 4; im++)
#pragma unroll
            for (int r = 0; r < 4; r++) {
                int row = m0 + wm + im * 16 + quad * 4 + r;
#pragma unroll
                for (int in = 0; in < NI; in++)
                    C[(size_t)row * N + ncol + in * 16 + c16] =
                        acc[im][in][r] + bv[in];
            }
    } else {
        if (ncol < 2 * C_) {
            const float fac = (ncol < C_) ? QSCALE : 1.0f;
            unsigned short* qkp = (unsigned short*)Cp;
#pragma unroll
            for (int im = 0; im < 4; im++)
#pragma unroll
                for (int r = 0; r < 4; r++) {
                    int row = m0 + wm + im * 16 + quad * 4 + r;
#pragma unroll
                    for (int in = 0; in < NI; in++)
                        qkp[(size_t)row * QK2_ + ncol + in * 16 + c16] =
                            f2b((acc[im][in][r] + bv[in]) * fac);
                }
        } else {                 // V -> vt[B,H,64,T]
#pragma unroll
            for (int im = 0; im < 4; im++) {
                int row0 = m0 + wm + im * 16 + quad * 4;
                int b  = row0 >> 11;
                int t0 = row0 & (T_ - 1);
#pragma unroll
                for (int in = 0; in < NI; in++) {
                    int dfull = ncol - 2 * C_ + in * 16 + c16;
                    short4v sv;
#pragma unroll
                    for (int r = 0; r < 4; r++)
                        sv[r] = (short)f2b(acc[im][in][r] + bv[in]);
                    *reinterpret_cast<short4v*>(
                        &vtp[(((size_t)(b << 10) + dfull) << 11) + t0]) = sv;
                }
            }
        }
    }
}

// ---------------------------------------------------------------------------
// One 64-key chunk, one wave: key-half ws x this wave's 32 q rows, all
// operands DIRECT FROM GLOBAL (line-exact: quads tile 64B lines).
// K: 4 x b128 (rows 32ws+c16, 32ws+16+c16; d-halves quad*8, 32+quad*8).
// V: 8 x b64 (rows d=dt*16+c16, keys ws*32+quad*4 and +16 -> interleaved
// PV window {sub0:quad*4+r, sub1:+16} matching pf packing).
// l via ones-MFMA: O1[qt] += mfma(pf[qt], ones) = per-row chunk sums.
// ---------------------------------------------------------------------------
#define ATTN_CHUNK(MASKED, kb)                                                \
{                                                                             \
    const unsigned short* kb0 = krow + (size_t)((kb) + ws * 32 + c16) * QK2_; \
    short8 kf00 = *reinterpret_cast<const short8*>(kb0 + quad * 8);           \
    short8 kf01 = *reinterpret_cast<const short8*>(kb0 + 32 + quad * 8);      \
    short8 kf10 = *reinterpret_cast<const short8*>(kb0 + 16 * QK2_ + quad * 8); \
    short8 kf11 = *reinterpret_cast<const short8*>(kb0 + 16 * QK2_ + 32 + quad * 8); \
    short8 vf[4];                                                             \
    _Pragma("unroll")                                                         \
    for (int dt = 0; dt < 4; dt++) {                                          \
        const unsigned short* vb = vrow + (size_t)(dt * 16 + c16) * T_ +      \
                                   (kb) + ws * 32 + quad * 4;                 \
        short4v v0 = *reinterpret_cast<const short4v*>(vb);                   \
        short4v v1 = *reinterpret_cast<const short4v*>(vb + 16);              \
        short8 vv;                                                            \
        vv[0] = v0[0]; vv[1] = v0[1]; vv[2] = v0[2]; vv[3] = v0[3];           \
        vv[4] = v1[0]; vv[5] = v1[1]; vv[6] = v1[2]; vv[7] = v1[3];           \
        vf[dt] = vv;                                                          \
    }                                                                         \
    short8 pf[2];                                                             \
    _Pragma("unroll")                                                         \
    for (int qt = 0; qt < 2; qt++) {                                          \
        floatx4 s0 = __builtin_amdgcn_mfma_f32_16x16x32_bf16(                 \
            kf00, af[qt][0], z, 0, 0, 0);                                     \
        s0 = __builtin_amdgcn_mfma_f32_16x16x32_bf16(                         \
            kf01, af[qt][1], s0, 0, 0, 0);                                    \
        floatx4 s1 = __builtin_amdgcn_mfma_f32_16x16x32_bf16(                 \
            kf10, af[qt][0], z, 0, 0, 0);                                     \
        s1 = __builtin_amdgcn_mfma_f32_16x16x32_bf16(                         \
            kf11, af[qt][1], s1, 0, 0, 0);                                    \
        short8 p8;                                                            \
        _Pragma("unroll")                                                     \
        for (int r = 0; r < 4; r++) {                                         \
            float p0, p1;                                                     \
            if (MASKED) {                                                     \
                int key0 = (kb) + ws * 32 + quad * 4 + r;                     \
                int qr = q0 + wq * 32 + qt * 16 + c16;                        \
                p0 = (key0 <= qr) ? fexp2(s0[r]) : 0.f;                       \
                p1 = (key0 + 16 <= qr) ? fexp2(s1[r]) : 0.f;                  \
            } else {                                                          \
                p0 = fexp2(s0[r]);                                            \
                p1 = fexp2(s1[r]);                                            \
            }                                                                 \
            p8[r] = (short)f2b(p0);                                           \
            p8[4 + r] = (short)f2b(p1);                                       \
        }                                                                     \
        pf[qt] = p8;                                                          \
    }                                                                         \
    _Pragma("unroll")                                                         \
    for (int qt = 0; qt < 2; qt++)                                            \
        O1[qt] = __builtin_amdgcn_mfma_f32_16x16x32_bf16(                     \
            pf[qt], ones, O1[qt], 0, 0, 0);                                   \
    _Pragma("unroll")                                                         \
    for (int dt = 0; dt < 4; dt++)                                            \
        _Pragma("unroll")                                                     \
        for (int qt = 0; qt < 2; qt++)                                        \
            O[qt][dt] = __builtin_amdgcn_mfma_f32_16x16x32_bf16(              \
                pf[qt], vf[dt], O[qt][dt], 0, 0, 0);                          \
}

// ---------------------------------------------------------------------------
// Flash attention, 2x2 wave split, zero-LDS main loop. Block = 256 thr =
// 4 waves; block t owns Q rows [64t,64t+64), nch=t+1, LPT. Wave w: q-half
// wq=w&1 (32 rows, Q in regs), key-half ws=w>>1 (keys 32ws..+32 of every
// chunk). No barriers in the loop; waves independent. Pair merge through
// a 20KB LDS buffer (one barrier). All O/O1 indices compile-time (rule
// #20). Fully-masked {wq0,ws1} diagonal corner skipped (wave-uniform).
// launch_bounds(256,3) -> 3 blocks/CU = 12 waves/CU.
// ---------------------------------------------------------------------------
__global__ __launch_bounds__(256, 3) void attn_mfma(
    const unsigned short* __restrict__ qk,
    const unsigned short* __restrict__ vt,
    unsigned short* __restrict__ y) {
    __shared__ __align__(16) float Of[4096];   // [wq][qt][dt][lane][4]
    __shared__ __align__(16) float Lb[1024];   // [wq][qt][lane][4] (O1 park)

    const int tid  = threadIdx.x;
    const int lane = tid & 63;
    const int w    = tid >> 6;          // 0..3
    const int wq   = w & 1;             // q-half
    const int ws   = w >> 1;            // key-half
    const int c16  = lane & 15;
    const int quad = lane >> 4;
    const int bh = blockIdx.x & 31;
    const int t  = 31 - (blockIdx.x >> 5);   // longest-first
    const int b  = bh >> 4;
    const int h  = bh & 15;
    const int q0 = t * 64;
    const int nch = t + 1;

    const unsigned short* qrow = qk + (size_t)b * T_ * QK2_ + h * HD_;
    const unsigned short* krow = qrow + C_;
    const unsigned short* vrow = vt + ((size_t)bh << 6) * T_;

    // Q in registers: af[qt][hh] = Q[q0+wq*32+qt*16+c16][hh*32+quad*8 ..+8]
    short8 af[2][2];
#pragma unroll
    for (int qt = 0; qt < 2; qt++)
#pragma unroll
        for (int hh = 0; hh < 2; hh++)
            af[qt][hh] = *reinterpret_cast<const short8*>(
                qrow + (size_t)(q0 + wq * 32 + qt * 16 + c16) * QK2_ +
                hh * 32 + quad * 8);

    floatx4 O[2][4] = {};
    floatx4 O1[2] = {};                  // row-sums l via ones-MFMA
    float lacc_unused = 0.f; (void)lacc_unused;
    const floatx4 z = {0.f, 0.f, 0.f, 0.f};
    short8 ones;
#pragma unroll
    for (int j = 0; j < 8; j++) ones[j] = (short)0x3F80;   // bf16 1.0

    for (int c = 0; c < nch; c++) {
        const int kb = c * 64;
        if (c + 1 < nch) {
            ATTN_CHUNK(0, kb)
        } else if (!(wq == 0 && ws == 1)) {
            // diagonal chunk; {wq0,ws1} corner is fully masked -> skip
            ATTN_CHUNK(1, kb)
        }
    }

    // ---- pair merge: O_total = O(ws=0) + O(ws=1) per q-half.
    // ws=1 parks O (32 f32/lane) + O1 in LDS; ws=0 partners add and write.
    if (ws) {
#pragma unroll
        for (int qt = 0; qt < 2; qt++) {
#pragma unroll
            for (int dt = 0; dt < 4; dt++)
                *reinterpret_cast<floatx4*>(
                    &Of[wq * 2048 + qt * 1024 + dt * 256 + lane * 4]) = O[qt][dt];
            *reinterpret_cast<floatx4*>(
                &Lb[wq * 512 + qt * 256 + lane * 4]) = O1[qt];
        }
    }
    __syncthreads();
    if (ws == 0) {
#pragma unroll
        for (int qt = 0; qt < 2; qt++) {
#pragma unroll
            for (int dt = 0; dt < 4; dt++)
                O[qt][dt] += *reinterpret_cast<const floatx4*>(
                    &Of[wq * 2048 + qt * 1024 + dt * 256 + lane * 4]);
            floatx4 lr = O1[qt] + *reinterpret_cast<const floatx4*>(
                    &Lb[wq * 512 + qt * 256 + lane * 4]);

            // write rows q0+wq*32+qt*16+quad*4+r, cols h*HD+dt*16+c16
#pragma unroll
            for (int dt = 0; dt < 4; dt++)
#pragma unroll
                for (int r = 0; r < 4; r++) {
                    float val = O[qt][dt][r] / fmaxf(lr[r], 1e-30f);
                    y[((size_t)b * T_ + q0 + wq * 32 + qt * 16 + quad * 4 + r)
                          * C_ + h * HD_ + dt * 16 + c16] = f2b(val);
                }
        }
    }
}

extern "C" void kernel_launch(void* const* d_in, const int* in_sizes, int n_in,
                              void* d_out, int out_size, void* d_ws, size_t ws_size,
                              hipStream_t stream) {
    const float* x     = (const float*)d_in[0];
    const float* w_qkv = (const float*)d_in[1];
    const float* b_qkv = (const float*)d_in[2];
    const float* w_out = (const float*)d_in[3];
    const float* b_out = (const float*)d_in[4];
    float* out = (float*)d_out;

    unsigned short* qkb = (unsigned short*)d_ws;                 // [4096][2048]
    unsigned short* vtb = qkb + (size_t)M_ * QK2_;               // [B,H,64,T]
    unsigned short* yb  = vtb + (size_t)B_ * H_ * HD_ * T_;      // [4096][1024]
    unsigned short* wt1 = yb + (size_t)M_ * C_;                  // [3072][1024]
    unsigned short* wt2 = wt1 + (size_t)N3_ * C_;                // [1024][1024]
    unsigned short* xb  = wt2 + (size_t)C_ * C_;                 // [4096][1024]

    prep<<<4096 + 1536 + 512, 256, 0, stream>>>(x, w_qkv, w_out, xb, wt1, wt2);

    gemm_glds<1, 128><<<(N3_ / 128) * (M_ / 128), 256, 0, stream>>>(
        xb, wt1, b_qkv, qkb, vtb, M_, N3_, C_);

    attn_mfma<<<B_ * H_ * 32, 256, 0, stream>>>(qkb, vtb, yb);

    gemm_glds<0, 64><<<(C_ / 64) * (M_ / 128), 256, 0, stream>>>(
        yb, wt2, b_out, out, nullptr, M_, C_, C_);
}